// Round 22
// baseline (12478.672 us; speedup 1.0000x reference)
//
#include <hip/hip_runtime.h>
#include <cstdint>
#include <cstddef>

typedef float f32x4 __attribute__((ext_vector_type(4)));
typedef __bf16 bfv8 __attribute__((ext_vector_type(8)));
typedef short sv4 __attribute__((ext_vector_type(4)));
typedef short sv8 __attribute__((ext_vector_type(8)));

__device__ __forceinline__ float b2f(short u) {
  union { unsigned int i; float f; } x;
  x.i = ((unsigned int)(unsigned short)u) << 16;
  return x.f;
}
__device__ __forceinline__ short f2b(float f) {
  union { float f; unsigned int i; } x; x.f = f;
  unsigned int r = x.i + 0x7fffu + ((x.i >> 16) & 1u);
  return (short)(unsigned short)(r >> 16);
}
__device__ __forceinline__ float wredsum(float v) {
#pragma unroll
  for (int m = 32; m >= 1; m >>= 1) v += __shfl_xor(v, m);
  return v;
}
__device__ __forceinline__ float softplus_f(float x) {
  return fmaxf(x, 0.f) + log1pf(expf(-fabsf(x)));
}
// paired-row stage inversion: granule p (16B) -> logical (row, kslot c)
__device__ __forceinline__ void pairmap(int p, int& rowL, int& cL) {
  int line = p >> 3;
  int within = (p & 7) * 16;
  int m = (2 * (line & 3)) << 4;
  int x = within ^ m;
  if (x < 64) { rowL = 2 * line;     cL = x >> 4; }
  else        { rowL = 2 * line + 1; cL = ((x ^ 16) >> 4) - 4; }
}

// ================ narrow LDS GEMM (r5/r7 proven) — drain votes ==============
template<int RELU, int KC, int NOUT, int SPLITA, int LOGITS, int NY>
__global__ __launch_bounds__(256)
void gemm_lds_k(const short* __restrict__ A, const short* __restrict__ BT,
                const float* __restrict__ bias, short* __restrict__ Cb,
                int M, int nvoff, const float* __restrict__ w3,
                float* __restrict__ lgout) {
  __shared__ char smem[32768];
  const int t = threadIdx.x;
  const int lane = t & 63;
  const int wid = t >> 6;
  const int wr = wid >> 1, wc = wid & 1;
  const int lr = lane & 15, lk = lane >> 4;

  constexpr int G = 8 * NY;
  int id = blockIdx.x;
  int NX = (int)gridDim.x / NY;
  int nxf = NX & ~7;
  int nfull_ids = nxf * NY;
  int bx, by;
  if (id < nfull_ids) {
    int g = id / G;
    int r = id - g * G;
    bx = g * 8 + (r & 7);
    by = r >> 3;
  } else {
    int rem = id - nfull_ids;
    int w = NX - nxf;
    bx = nxf + rem % w;
    by = rem / w;
  }
  const int m0 = bx * 128;
  const int n0 = by * 128;

  f32x4 acc[4][4];
#pragma unroll
  for (int i = 0; i < 4; ++i)
#pragma unroll
    for (int j = 0; j < 4; ++j) { acc[i][j][0]=0.f; acc[i][j][1]=0.f; acc[i][j][2]=0.f; acc[i][j][3]=0.f; }

  for (int k0 = 0; k0 < KC; k0 += 64) {
#pragma unroll
    for (int i = 0; i < 4; ++i) {
      int p = t + i * 256;
      int row = p >> 3, chunk = p & 7;
      int kb = (chunk * 16) ^ ((row & 7) << 4);
      {
        int rg = m0 + row; if (rg >= M) rg = M - 1;
        const short* src;
        if (SPLITA) {
          int keff = k0 + (kb >> 1);
          src = (keff < 256) ? (A + (size_t)rg * 256 + keff)
                             : (A + (size_t)(rg + nvoff) * 256 + (keff - 256));
        } else {
          src = A + (size_t)rg * KC + k0 + (kb >> 1);
        }
        int dstb = (wid * 64 + i * 256) * 16;
        __builtin_amdgcn_global_load_lds(
            (const __attribute__((address_space(1))) void*)src,
            (__attribute__((address_space(3))) void*)(smem + dstb), 16, 0, 0);
      }
      {
        const short* src = BT + (size_t)(n0 + row) * KC + k0 + (kb >> 1);
        int dstb = 16384 + (wid * 64 + i * 256) * 16;
        __builtin_amdgcn_global_load_lds(
            (const __attribute__((address_space(1))) void*)src,
            (__attribute__((address_space(3))) void*)(smem + dstb), 16, 0, 0);
      }
    }
    __syncthreads();

#pragma unroll
    for (int kk = 0; kk < 64; kk += 32) {
      bfv8 af[4], bfr[4];
#pragma unroll
      for (int mf = 0; mf < 4; ++mf) {
        int row = wr * 64 + mf * 16 + lr;
        int kb = (kk * 2 + lk * 16) ^ ((row & 7) << 4);
        af[mf] = *(const bfv8*)(smem + row * 128 + kb);
      }
#pragma unroll
      for (int nf = 0; nf < 4; ++nf) {
        int row = wc * 64 + nf * 16 + lr;
        int kb = (kk * 2 + lk * 16) ^ ((row & 7) << 4);
        bfr[nf] = *(const bfv8*)(smem + 16384 + row * 128 + kb);
      }
#pragma unroll
      for (int mf = 0; mf < 4; ++mf)
#pragma unroll
        for (int nf = 0; nf < 4; ++nf)
          acc[mf][nf] = __builtin_amdgcn_mfma_f32_16x16x32_bf16(af[mf], bfr[nf], acc[mf][nf], 0, 0, 0);
    }
    __syncthreads();
  }

  if constexpr (LOGITS) {
#pragma unroll
    for (int mf = 0; mf < 4; ++mf) {
#pragma unroll
      for (int q = 0; q < 4; ++q) {
        float pd = 0.f;
#pragma unroll
        for (int nf = 0; nf < 4; ++nf) {
          int col = n0 + wc * 64 + nf * 16 + lr;
          float v = fmaxf(acc[mf][nf][q] + bias[col], 0.f);
          pd += v * w3[col];
        }
#pragma unroll
        for (int msk = 8; msk >= 1; msk >>= 1) pd += __shfl_xor(pd, msk);
        int row = m0 + wr * 64 + mf * 16 + lk * 4 + q;
        if (lr == 0 && row < M) lgout[(size_t)row * 8 + (n0 >> 7) * 2 + wc] = pd;
      }
    }
  } else {
#pragma unroll
    for (int nf = 0; nf < 4; ++nf) {
      int col = n0 + wc * 64 + nf * 16 + lr;
      float bv = bias[col];
#pragma unroll
      for (int mf = 0; mf < 4; ++mf) {
#pragma unroll
        for (int q = 0; q < 4; ++q) {
          int row = m0 + wr * 64 + mf * 16 + lk * 4 + q;
          if (row < M) {
            float v = acc[mf][nf][q] + bv;
            if (RELU) v = fmaxf(v, 0.f);
            Cb[(size_t)row * NOUT + col] = f2b(v);
          }
        }
      }
    }
  }
}

// ================ 3-segment GEMM (r21 proven): loop + coalesced C-writes ====
struct Seg {
  const short* A; const short* BT; const float* bias;
  short* C0; short* C1;
  int M, nblk, ny, cstride, kc;
  int relu, splitA, logits, nvoff;
};

__global__ __launch_bounds__(256)
void gemm_multi3_k(Seg s0, Seg s1, Seg s2,
                   const float* __restrict__ w3, float* __restrict__ lgout) {
  __shared__ char smem[32768];
  const int t = threadIdx.x;
  const int lane = t & 63;
  const int wid = t >> 6;
  const int wr = wid >> 1, wc = wid & 1;
  const int lr = lane & 15, lk = lane >> 4;

  int id = blockIdx.x;
  Seg s;
  if (id < s0.nblk) { s = s0; }
  else if (id < s0.nblk + s1.nblk) { s = s1; id -= s0.nblk; }
  else { s = s2; id -= s0.nblk + s1.nblk; }

  int NX = s.nblk / s.ny;
  int nxf = NX & ~7;
  int nfull = nxf * s.ny;
  int bx, by;
  if (id < nfull) {
    int G = 8 * s.ny;
    int g = id / G;
    int r = id - g * G;
    bx = g * 8 + (r & 7);
    by = r >> 3;
  } else {
    int rem = id - nfull;
    int w = NX - nxf;
    bx = nxf + rem % w;
    by = rem / w;
  }
  const int m0 = bx * 128;
  const int nrow0 = by * 128;

  f32x4 acc[4][4];
#pragma unroll
  for (int i = 0; i < 4; ++i)
#pragma unroll
    for (int j = 0; j < 4; ++j) { acc[i][j][0]=0.f; acc[i][j][1]=0.f; acc[i][j][2]=0.f; acc[i][j][3]=0.f; }

  for (int k0 = 0; k0 < s.kc; k0 += 64) {
#pragma unroll
    for (int i = 0; i < 4; ++i) {
      int p = t + i * 256;
      int row = p >> 3, chunk = p & 7;
      int kb = (chunk * 16) ^ ((row & 7) << 4);
      {
        int rg = m0 + row; if (rg >= s.M) rg = s.M - 1;
        const short* src;
        if (s.splitA) {
          int keff = k0 + (kb >> 1);
          src = (keff < 256) ? (s.A + (size_t)rg * 256 + keff)
                             : (s.A + (size_t)(rg + s.nvoff) * 256 + (keff - 256));
        } else {
          src = s.A + (size_t)rg * s.kc + k0 + (kb >> 1);
        }
        int dstb = (wid * 64 + i * 256) * 16;
        __builtin_amdgcn_global_load_lds(
            (const __attribute__((address_space(1))) void*)src,
            (__attribute__((address_space(3))) void*)(smem + dstb), 16, 0, 0);
      }
      {
        const short* src = s.BT + (size_t)(nrow0 + row) * s.kc + k0 + (kb >> 1);
        int dstb = 16384 + (wid * 64 + i * 256) * 16;
        __builtin_amdgcn_global_load_lds(
            (const __attribute__((address_space(1))) void*)src,
            (__attribute__((address_space(3))) void*)(smem + dstb), 16, 0, 0);
      }
    }
    __syncthreads();

#pragma unroll
    for (int kk = 0; kk < 64; kk += 32) {
      bfv8 af[4], bfr[4];
#pragma unroll
      for (int mf = 0; mf < 4; ++mf) {
        int row = wr * 64 + mf * 16 + lr;
        int kb = (kk * 2 + lk * 16) ^ ((row & 7) << 4);
        af[mf] = *(const bfv8*)(smem + row * 128 + kb);
      }
#pragma unroll
      for (int nf = 0; nf < 4; ++nf) {
        int row = wc * 64 + nf * 16 + lr;
        int kb = (kk * 2 + lk * 16) ^ ((row & 7) << 4);
        bfr[nf] = *(const bfv8*)(smem + 16384 + row * 128 + kb);
      }
#pragma unroll
      for (int mf = 0; mf < 4; ++mf)
#pragma unroll
        for (int nf = 0; nf < 4; ++nf)
          acc[mf][nf] = __builtin_amdgcn_mfma_f32_16x16x32_bf16(af[mf], bfr[nf], acc[mf][nf], 0, 0, 0);
    }
    __syncthreads();
  }

  if (s.logits) {
#pragma unroll
    for (int mf = 0; mf < 4; ++mf) {
#pragma unroll
      for (int q = 0; q < 4; ++q) {
        float pd = 0.f;
#pragma unroll
        for (int nf = 0; nf < 4; ++nf) {
          int col = nrow0 + wc * 64 + nf * 16 + lr;
          float v = fmaxf(acc[mf][nf][q] + s.bias[col], 0.f);
          pd += v * w3[col];
        }
#pragma unroll
        for (int msk = 8; msk >= 1; msk >>= 1) pd += __shfl_xor(pd, msk);
        int row = m0 + wr * 64 + mf * 16 + lk * 4 + q;
        if (lr == 0 && row < s.M) lgout[(size_t)row * 8 + by * 2 + wc] = pd;
      }
    }
  } else {
    short* Cb; int colb;
    if (s.C1) {
      int h = s.ny >> 1;
      Cb = (by < h) ? s.C0 : s.C1;
      colb = (by % h) * 128;
    } else {
      Cb = s.C0;
      colb = by * 128;
    }
    // stage C tile (128x128 bf16 = 32KB) into LDS, XOR-swizzled per row
#pragma unroll
    for (int nf = 0; nf < 4; ++nf) {
      int cl = wc * 64 + nf * 16 + lr;
      float bv = s.bias[nrow0 + cl];
#pragma unroll
      for (int mf = 0; mf < 4; ++mf) {
#pragma unroll
        for (int q = 0; q < 4; ++q) {
          int rloc = wr * 64 + mf * 16 + lk * 4 + q;
          float v = acc[mf][nf][q] + bv;
          if (s.relu) v = fmaxf(v, 0.f);
          int byte = rloc * 256 + ((cl * 2) ^ ((rloc & 7) << 4));
          *(short*)(smem + byte) = f2b(v);
        }
      }
    }
    __syncthreads();
    // coalesced 16B stores: 16 lanes cover a full 256B row (chunk-permuted)
#pragma unroll
    for (int i = 0; i < 8; ++i) {
      int p = t + i * 256;
      int rloc = p >> 4, chunk = p & 15;
      int grow = m0 + rloc;
      if (grow < s.M) {
        int gcol = colb + ((chunk * 8) ^ ((rloc & 7) << 3));   // in shorts
        *(sv8*)(Cb + (size_t)grow * s.cstride + gcol) =
            *(const sv8*)(smem + rloc * 256 + chunk * 16);
      }
    }
  }
}

// ================ fused 3-layer MLP + residual + LN, 52KB LDS ===============
// r22: paired-row stage layout for A/W regions (conflict-free ds_read_b128).
// LDS: Astage/LN [0,4K) Wstage [4K,20K) h [20K,52K).
__global__ __launch_bounds__(512)
void mlp3ln_k(const short* __restrict__ A, const short* __restrict__ W1T,
              const short* __restrict__ W2T, const short* __restrict__ W3T,
              const float* __restrict__ b1, const float* __restrict__ b2,
              const float* __restrict__ b3, const float* __restrict__ g,
              const float* __restrict__ be, short* __restrict__ outp, int M) {
  __shared__ char smem[53248];
  const int t = threadIdx.x;
  const int lane = t & 63;
  const int wid = t >> 6;               // 0..7
  const int wr = wid >> 2, wc = wid & 3;
  const int lr = lane & 15, lk = lane >> 4;
  const int m0 = blockIdx.x * 64;

  float* lnS = (float*)smem;            // [4][64], overlaps dead A-stage region
  float* lnQ = (float*)(smem + 1024);

  // ---- phase 1: h1 = relu(A @ W1 + b1) -> LDS [20K,52K)
  f32x4 acc[2][4];
#pragma unroll
  for (int i = 0; i < 2; ++i)
#pragma unroll
    for (int j = 0; j < 4; ++j) { acc[i][j][0]=0.f; acc[i][j][1]=0.f; acc[i][j][2]=0.f; acc[i][j][3]=0.f; }

  for (int k0 = 0; k0 < 256; k0 += 32) {
    if (wid < 4) {                        // A chunk [64 rows][32 k], paired-row
      int rowL, cL; pairmap(t, rowL, cL);
      int rg = m0 + rowL; if (rg >= M) rg = M - 1;
      const short* src = A + (size_t)rg * 256 + k0 + cL * 8;
      __builtin_amdgcn_global_load_lds(
          (const __attribute__((address_space(1))) void*)src,
          (__attribute__((address_space(3))) void*)(smem + wid * 1024), 16, 0, 0);
    }
#pragma unroll
    for (int i = 0; i < 2; ++i) {         // W1 chunk [256 cols][32 k], paired-row
      int p = t + i * 512;
      int rowL, cL; pairmap(p, rowL, cL);
      const short* src = W1T + (size_t)rowL * 256 + k0 + cL * 8;
      __builtin_amdgcn_global_load_lds(
          (const __attribute__((address_space(1))) void*)src,
          (__attribute__((address_space(3))) void*)(smem + 4096 + (wid * 64 + i * 512) * 16), 16, 0, 0);
    }
    __syncthreads();

    bfv8 af[2], bfr[4];
#pragma unroll
    for (int mf = 0; mf < 2; ++mf) {
      int row = wr * 32 + mf * 16 + lr;
      int byte = (row >> 1) * 128 + ((lk * 16 + (row & 1) * 64) ^ ((row & 7) << 4));
      af[mf] = *(const bfv8*)(smem + byte);
    }
#pragma unroll
    for (int nf = 0; nf < 4; ++nf) {
      int row = wc * 64 + nf * 16 + lr;
      int byte = 4096 + (row >> 1) * 128 + ((lk * 16 + (row & 1) * 64) ^ ((row & 7) << 4));
      bfr[nf] = *(const bfv8*)(smem + byte);
    }
#pragma unroll
    for (int mf = 0; mf < 2; ++mf)
#pragma unroll
      for (int nf = 0; nf < 4; ++nf)
        acc[mf][nf] = __builtin_amdgcn_mfma_f32_16x16x32_bf16(af[mf], bfr[nf], acc[mf][nf], 0, 0, 0);
    __syncthreads();
  }

  // write h1 into LDS [20K,52K): row*512 + ((col*2) ^ ((row&7)<<4))
#pragma unroll
  for (int mf = 0; mf < 2; ++mf) {
#pragma unroll
    for (int nf = 0; nf < 4; ++nf) {
      int col = wc * 64 + nf * 16 + lr;
      float bv = b1[col];
#pragma unroll
      for (int q = 0; q < 4; ++q) {
        int row = wr * 32 + mf * 16 + lk * 4 + q;
        float v = fmaxf(acc[mf][nf][q] + bv, 0.f);
        int byte = 20480 + row * 512 + ((col * 2) ^ ((row & 7) << 4));
        *(short*)(smem + byte) = f2b(v);
      }
    }
  }

  // ---- phase 2: acc2 = h1 @ W2
  f32x4 acc2[2][4];
#pragma unroll
  for (int i = 0; i < 2; ++i)
#pragma unroll
    for (int j = 0; j < 4; ++j) { acc2[i][j][0]=0.f; acc2[i][j][1]=0.f; acc2[i][j][2]=0.f; acc2[i][j][3]=0.f; }

  for (int k0 = 0; k0 < 256; k0 += 32) {
#pragma unroll
    for (int i = 0; i < 2; ++i) {
      int p = t + i * 512;
      int rowL, cL; pairmap(p, rowL, cL);
      const short* src = W2T + (size_t)rowL * 256 + k0 + cL * 8;
      __builtin_amdgcn_global_load_lds(
          (const __attribute__((address_space(1))) void*)src,
          (__attribute__((address_space(3))) void*)(smem + 4096 + (wid * 64 + i * 512) * 16), 16, 0, 0);
    }
    __syncthreads();   // h1 writes (first iter) + W2 stage visible

    bfv8 af[2], bfr[4];
#pragma unroll
    for (int mf = 0; mf < 2; ++mf) {
      int row = wr * 32 + mf * 16 + lr;
      int kb = (k0 * 2 + lk * 16) ^ ((row & 7) << 4);
      af[mf] = *(const bfv8*)(smem + 20480 + row * 512 + kb);
    }
#pragma unroll
    for (int nf = 0; nf < 4; ++nf) {
      int row = wc * 64 + nf * 16 + lr;
      int byte = 4096 + (row >> 1) * 128 + ((lk * 16 + (row & 1) * 64) ^ ((row & 7) << 4));
      bfr[nf] = *(const bfv8*)(smem + byte);
    }
#pragma unroll
    for (int mf = 0; mf < 2; ++mf)
#pragma unroll
      for (int nf = 0; nf < 4; ++nf)
        acc2[mf][nf] = __builtin_amdgcn_mfma_f32_16x16x32_bf16(af[mf], bfr[nf], acc2[mf][nf], 0, 0, 0);
    __syncthreads();   // all h1 reads for this chunk done
  }

  // h2 = relu(acc2 + b2) overwrites the h-buffer (h1 dead)
#pragma unroll
  for (int mf = 0; mf < 2; ++mf) {
#pragma unroll
    for (int nf = 0; nf < 4; ++nf) {
      int col = wc * 64 + nf * 16 + lr;
      float bv = b2[col];
#pragma unroll
      for (int q = 0; q < 4; ++q) {
        int row = wr * 32 + mf * 16 + lk * 4 + q;
        float v = fmaxf(acc2[mf][nf][q] + bv, 0.f);
        int byte = 20480 + row * 512 + ((col * 2) ^ ((row & 7) << 4));
        *(short*)(smem + byte) = f2b(v);
      }
    }
  }

  // ---- phase 3: acc3 = h2 @ W3 ; epilogue residual + LN
  f32x4 acc3[2][4];
#pragma unroll
  for (int i = 0; i < 2; ++i)
#pragma unroll
    for (int j = 0; j < 4; ++j) { acc3[i][j][0]=0.f; acc3[i][j][1]=0.f; acc3[i][j][2]=0.f; acc3[i][j][3]=0.f; }

  for (int k0 = 0; k0 < 256; k0 += 32) {
#pragma unroll
    for (int i = 0; i < 2; ++i) {
      int p = t + i * 512;
      int rowL, cL; pairmap(p, rowL, cL);
      const short* src = W3T + (size_t)rowL * 256 + k0 + cL * 8;
      __builtin_amdgcn_global_load_lds(
          (const __attribute__((address_space(1))) void*)src,
          (__attribute__((address_space(3))) void*)(smem + 4096 + (wid * 64 + i * 512) * 16), 16, 0, 0);
    }
    __syncthreads();   // h2 writes (first iter) + W3 stage visible

    bfv8 af[2], bfr[4];
#pragma unroll
    for (int mf = 0; mf < 2; ++mf) {
      int row = wr * 32 + mf * 16 + lr;
      int kb = (k0 * 2 + lk * 16) ^ ((row & 7) << 4);
      af[mf] = *(const bfv8*)(smem + 20480 + row * 512 + kb);
    }
#pragma unroll
    for (int nf = 0; nf < 4; ++nf) {
      int row = wc * 64 + nf * 16 + lr;
      int byte = 4096 + (row >> 1) * 128 + ((lk * 16 + (row & 1) * 64) ^ ((row & 7) << 4));
      bfr[nf] = *(const bfv8*)(smem + byte);
    }
#pragma unroll
    for (int mf = 0; mf < 2; ++mf)
#pragma unroll
      for (int nf = 0; nf < 4; ++nf)
        acc3[mf][nf] = __builtin_amdgcn_mfma_f32_16x16x32_bf16(af[mf], bfr[nf], acc3[mf][nf], 0, 0, 0);
    __syncthreads();
  }

  // epilogue: + b3 + residual(A) -> row LayerNorm -> out
#pragma unroll
  for (int nf = 0; nf < 4; ++nf) {
    int col = wc * 64 + nf * 16 + lr;
    float bv = b3[col];
#pragma unroll
    for (int mf = 0; mf < 2; ++mf) {
#pragma unroll
      for (int q = 0; q < 4; ++q) {
        int row = m0 + wr * 32 + mf * 16 + lk * 4 + q;
        int rr = row < M ? row : M - 1;
        acc3[mf][nf][q] += bv + b2f(A[(size_t)rr * 256 + col]);
      }
    }
  }
#pragma unroll
  for (int mf = 0; mf < 2; ++mf) {
#pragma unroll
    for (int q = 0; q < 4; ++q) {
      float s  = acc3[mf][0][q] + acc3[mf][1][q] + acc3[mf][2][q] + acc3[mf][3][q];
      float ss = acc3[mf][0][q]*acc3[mf][0][q] + acc3[mf][1][q]*acc3[mf][1][q]
               + acc3[mf][2][q]*acc3[mf][2][q] + acc3[mf][3][q]*acc3[mf][3][q];
#pragma unroll
      for (int msk = 8; msk >= 1; msk >>= 1) {
        s  += __shfl_xor(s, msk);
        ss += __shfl_xor(ss, msk);
      }
      if (lr == 0) {
        int rloc = wr * 32 + mf * 16 + lk * 4 + q;
        lnS[wc * 64 + rloc] = s;
        lnQ[wc * 64 + rloc] = ss;
      }
    }
  }
  __syncthreads();
#pragma unroll
  for (int mf = 0; mf < 2; ++mf) {
#pragma unroll
    for (int q = 0; q < 4; ++q) {
      int rloc = wr * 32 + mf * 16 + lk * 4 + q;
      float S  = lnS[rloc] + lnS[64 + rloc] + lnS[128 + rloc] + lnS[192 + rloc];
      float SQ = lnQ[rloc] + lnQ[64 + rloc] + lnQ[128 + rloc] + lnQ[192 + rloc];
      float mu = S * (1.f/256.f);
      float var = SQ * (1.f/256.f) - mu * mu;
      float rs = rsqrtf(fmaxf(var, 0.f) + 1e-3f);
      int row = m0 + rloc;
      if (row < M) {
#pragma unroll
        for (int nf = 0; nf < 4; ++nf) {
          int col = wc * 64 + nf * 16 + lr;
          float y = (acc3[mf][nf][q] - mu) * rs * g[col] + be[col];
          outp[(size_t)row * 256 + col] = f2b(y);
        }
      }
    }
  }
}

// ---------------- transpose W[K,N] (f32) -> WT[N,K] (bf16)
__global__ void transpose_k(const float* __restrict__ W, short* __restrict__ WT, int Kd, int Nd) {
  int idx = blockIdx.x * 256 + threadIdx.x;
  if (idx >= Kd * Nd) return;
  int k = idx / Nd, n = idx - k * Nd;
  WT[(size_t)n * Kd + k] = f2b(W[idx]);
}

__global__ void init_state_k(const float* __restrict__ initrow, short* __restrict__ st, int rows) {
  int idx = blockIdx.x * 256 + threadIdx.x;
  if (idx >= rows * 256) return;
  st[idx] = f2b(initrow[idx & 255] * 0.0625f);
}

__global__ void zero_i32_k(int* __restrict__ p, int n) {
  int i = blockIdx.x * 256 + threadIdx.x;
  if (i < n) p[i] = 0;
}
__global__ void zero_f32_k(float* __restrict__ p, int n) {
  int i = blockIdx.x * 256 + threadIdx.x;
  if (i < n) p[i] = 0.f;
}

// ---------------- clause attention (r8-proven math, KV interleaved)
__global__ void clause_attn_k(const short* __restrict__ Q, const short* __restrict__ KV,
                              const int* __restrict__ lit_idx,
                              const short* __restrict__ cin, const float* __restrict__ g,
                              const float* __restrict__ be, short* __restrict__ ob, int NC) {
  int i = blockIdx.x * 4 + (threadIdx.x >> 6);
  if (i >= NC) return;
  int lane = threadIdx.x & 63;
  int d0 = lane * 4;
  sv4 qv = *(const sv4*)(Q + (size_t)i * 256 + d0);
  int L0 = lit_idx[3*i], L1 = lit_idx[3*i+1], L2 = lit_idx[3*i+2];
  float s0, s1, s2;
  {
    sv4 k0 = *(const sv4*)(KV + (size_t)L0 * 512 + d0);
    sv4 k1 = *(const sv4*)(KV + (size_t)L1 * 512 + d0);
    sv4 k2 = *(const sv4*)(KV + (size_t)L2 * 512 + d0);
    float d0s = 0.f, d1s = 0.f, d2s = 0.f;
#pragma unroll
    for (int t = 0; t < 4; ++t) {
      float qf = b2f(qv[t]);
      d0s += qf * b2f(k0[t]);
      d1s += qf * b2f(k1[t]);
      d2s += qf * b2f(k2[t]);
    }
    s0 = wredsum(d0s) * 0.0625f;
    s1 = wredsum(d1s) * 0.0625f;
    s2 = wredsum(d2s) * 0.0625f;
  }
  float m = fmaxf(s0, fmaxf(s1, s2));
  float e0 = expf(s0 - m), e1 = expf(s1 - m), e2 = expf(s2 - m);
  float inv = 1.f / (e0 + e1 + e2 + 1e-9f);
  float a0 = e0 * inv, a1 = e1 * inv, a2 = e2 * inv;
  sv4 v0 = *(const sv4*)(KV + (size_t)L0 * 512 + 256 + d0);
  sv4 v1 = *(const sv4*)(KV + (size_t)L1 * 512 + 256 + d0);
  sv4 v2 = *(const sv4*)(KV + (size_t)L2 * 512 + 256 + d0);
  sv4 cv = *(const sv4*)(cin + (size_t)i * 256 + d0);
  float x[4];
#pragma unroll
  for (int t = 0; t < 4; ++t)
    x[t] = b2f(cv[t]) + a0*b2f(v0[t]) + a1*b2f(v1[t]) + a2*b2f(v2[t]);
  float s = x[0]+x[1]+x[2]+x[3];
  float ss = x[0]*x[0]+x[1]*x[1]+x[2]*x[2]+x[3]*x[3];
  s = wredsum(s); ss = wredsum(ss);
  float mu = s * (1.f/256.f);
  float var = ss * (1.f/256.f) - mu*mu;
  float rs = rsqrtf(fmaxf(var, 0.f) + 1e-3f);
  f32x4 gv = *(const f32x4*)(g + d0);
  f32x4 bv = *(const f32x4*)(be + d0);
  sv4 yb;
#pragma unroll
  for (int t = 0; t < 4; ++t) yb[t] = f2b((x[t]-mu)*rs*gv[t] + bv[t]);
  *(sv4*)(ob + (size_t)i*256 + d0) = yb;
}

// ---------------- literal attention (r11-proven, 4-edge batch)
__global__ void lit_attn_k(const short* __restrict__ Q, const short* __restrict__ K,
                           const short* __restrict__ V, const int* __restrict__ offs,
                           const int* __restrict__ elist, const short* __restrict__ lin,
                           const float* __restrict__ g, const float* __restrict__ be,
                           short* __restrict__ ob, int NLIT, int nv) {
  int q = blockIdx.x * 4 + (threadIdx.x >> 6);
  if (q >= NLIT) return;
  int lane = threadIdx.x & 63;
  int o0 = offs[q], o1 = offs[q+1];
  int r = (q < nv) ? q + nv : q - nv;
  int d0 = lane * 4;
  sv4 qv = *(const sv4*)(Q + (size_t)q * 256 + d0);
  float m = -1e30f, ssum = 0.f;
  float acc[4] = {0.f, 0.f, 0.f, 0.f};
  for (int j = o0; j < o1; j += 4) {
    int nb = o1 - j; if (nb > 4) nb = 4;
    sv4 kr0, kr1, kr2, kr3, vr0, vr1, vr2, vr3;
    float dd0, dd1, dd2, dd3;
    {
      int e0i = elist[j];
      int e1i = elist[(1 < nb) ? j + 1 : j];
      int e2i = elist[(2 < nb) ? j + 2 : j];
      int e3i = elist[(3 < nb) ? j + 3 : j];
      size_t c0 = (size_t)(e0i / 3) * 256, c1 = (size_t)(e1i / 3) * 256;
      size_t c2 = (size_t)(e2i / 3) * 256, c3 = (size_t)(e3i / 3) * 256;
      kr0 = *(const sv4*)(K + c0 + d0); vr0 = *(const sv4*)(V + c0 + d0);
      kr1 = *(const sv4*)(K + c1 + d0); vr1 = *(const sv4*)(V + c1 + d0);
      kr2 = *(const sv4*)(K + c2 + d0); vr2 = *(const sv4*)(V + c2 + d0);
      kr3 = *(const sv4*)(K + c3 + d0); vr3 = *(const sv4*)(V + c3 + d0);
    }
    dd0 = dd1 = dd2 = dd3 = 0.f;
#pragma unroll
    for (int t = 0; t < 4; ++t) {
      float qf = b2f(qv[t]);
      dd0 += qf * b2f(kr0[t]);
      dd1 += qf * b2f(kr1[t]);
      dd2 += qf * b2f(kr2[t]);
      dd3 += qf * b2f(kr3[t]);
    }
#pragma unroll
    for (int msk = 32; msk >= 1; msk >>= 1) {
      dd0 += __shfl_xor(dd0, msk);
      dd1 += __shfl_xor(dd1, msk);
      dd2 += __shfl_xor(dd2, msk);
      dd3 += __shfl_xor(dd3, msk);
    }
    float ds[4] = {dd0, dd1, dd2, dd3};
    sv4 vrs[4] = {vr0, vr1, vr2, vr3};
#pragma unroll
    for (int s = 0; s < 4; ++s) {
      if (s < nb) {
        float d = ds[s] * 0.0625f;
        float nm = fmaxf(m, d);
        float rm = expf(m - nm);
        float w  = expf(d - nm);
        ssum = ssum * rm + w;
#pragma unroll
        for (int t = 0; t < 4; ++t) acc[t] = acc[t] * rm + w * b2f(vrs[s][t]);
        m = nm;
      }
    }
  }
  float winv = (o1 > o0) ? 1.f / (ssum + 1e-9f) : 0.f;
  sv4 lv = *(const sv4*)(lin + (size_t)r * 256 + d0);
  float x[4];
#pragma unroll
  for (int t = 0; t < 4; ++t) x[t] = b2f(lv[t]) + acc[t] * winv;
  float s = x[0]+x[1]+x[2]+x[3];
  float ss = x[0]*x[0]+x[1]*x[1]+x[2]*x[2]+x[3]*x[3];
  s = wredsum(s); ss = wredsum(ss);
  float mu = s * (1.f/256.f);
  float var = ss * (1.f/256.f) - mu*mu;
  float rs = rsqrtf(fmaxf(var, 0.f) + 1e-3f);
  f32x4 gv = *(const f32x4*)(g + d0);
  f32x4 bv = *(const f32x4*)(be + d0);
  sv4 yb;
#pragma unroll
  for (int t = 0; t < 4; ++t) yb[t] = f2b((x[t]-mu)*rs*gv[t] + bv[t]);
  *(sv4*)(ob + (size_t)r*256 + d0) = yb;
}

// ---------------- loss (lg8: 8 partials/variable, + b3)
__global__ void loss_k(const int* __restrict__ clauses, const float* __restrict__ lg8,
                       const float* __restrict__ b3p, float* __restrict__ total, int NC) {
  __shared__ float red[256];
  int i = blockIdx.x * 256 + threadIdx.x;
  float acc = 0.f;
  if (i < NC) {
    float b3v = b3p[0];
    float cs = 0.f;
#pragma unroll
    for (int j = 0; j < 3; ++j) {
      int lit = clauses[3*i + j];
      int v = (lit > 0 ? lit : -lit) - 1;
      float sg = (lit > 0) ? 1.f : -1.f;
      f32x4 a = *(const f32x4*)(lg8 + (size_t)v * 8);
      f32x4 b = *(const f32x4*)(lg8 + (size_t)v * 8 + 4);
      float lv = ((a[0]+a[1])+(a[2]+a[3])) + ((b[0]+b[1])+(b[2]+b[3])) + b3v;
      cs += softplus_f(lv * sg);
    }
    float t = softplus_f(-cs);
    acc = t * t;
  }
  red[threadIdx.x] = acc;
  __syncthreads();
  for (int s = 128; s > 0; s >>= 1) {
    if (threadIdx.x < s) red[threadIdx.x] += red[threadIdx.x + s];
    __syncthreads();
  }
  if (threadIdx.x == 0) atomicAdd(total, red[0]);
}

__global__ void writeout_k(const float* __restrict__ lg8, const float* __restrict__ b3p,
                           const float* __restrict__ total, float* __restrict__ out, int nv) {
  int i = blockIdx.x * 256 + threadIdx.x;
  if (i < nv) {
    f32x4 a = *(const f32x4*)(lg8 + (size_t)i * 8);
    f32x4 b = *(const f32x4*)(lg8 + (size_t)i * 8 + 4);
    out[i] = ((a[0]+a[1])+(a[2]+a[3])) + ((b[0]+b[1])+(b[2]+b[3])) + b3p[0];
  } else if (i == nv) {
    out[nv] = total[0] * (1.f/32.f);
  }
}

// ---------------- CSR build
__global__ void hist_k(const int* __restrict__ lit_idx, int* __restrict__ cnt, int E) {
  int e = blockIdx.x * 256 + threadIdx.x;
  if (e < E) atomicAdd(&cnt[lit_idx[e]], 1);
}
__global__ void scan1_k(const int* __restrict__ cnt, int* __restrict__ excl,
                        int* __restrict__ bsum, int n) {
  __shared__ int sm[256];
  int i = blockIdx.x * 256 + threadIdx.x;
  int v = (i < n) ? cnt[i] : 0;
  sm[threadIdx.x] = v;
  __syncthreads();
  for (int o = 1; o < 256; o <<= 1) {
    int add = (threadIdx.x >= o) ? sm[threadIdx.x - o] : 0;
    __syncthreads();
    sm[threadIdx.x] += add;
    __syncthreads();
  }
  if (i < n) excl[i] = sm[threadIdx.x] - v;
  if (threadIdx.x == 255) bsum[blockIdx.x] = sm[255];
}
__global__ void scan2_k(int* __restrict__ bsum, int nb) {
  __shared__ int sm[256];
  int v = (threadIdx.x < nb) ? bsum[threadIdx.x] : 0;
  sm[threadIdx.x] = v;
  __syncthreads();
  for (int o = 1; o < 256; o <<= 1) {
    int add = (threadIdx.x >= o) ? sm[threadIdx.x - o] : 0;
    __syncthreads();
    sm[threadIdx.x] += add;
    __syncthreads();
  }
  if (threadIdx.x < nb) bsum[threadIdx.x] = sm[threadIdx.x] - v;
}
__global__ void scan3_k(const int* __restrict__ excl, const int* __restrict__ bsum,
                        int* __restrict__ offs, int n, int E) {
  int i = blockIdx.x * 256 + threadIdx.x;
  if (i < n) offs[i] = excl[i] + bsum[i >> 8];
  if (i == 0) offs[n] = E;
}
__global__ void fill_k(const int* __restrict__ lit_idx, const int* __restrict__ offs,
                       int* __restrict__ cur, int* __restrict__ elist, int E) {
  int e = blockIdx.x * 256 + threadIdx.x;
  if (e >= E) return;
  int l = lit_idx[e];
  int p = offs[l] + atomicAdd(&cur[l], 1);
  elist[p] = e;
}

extern "C" void kernel_launch(void* const* d_in, const int* in_sizes, int n_in,
                              void* d_out, int out_size, void* d_ws, size_t ws_size,
                              hipStream_t stream) {
  (void)n_in;
  const float* L_init = (const float*)d_in[0];
  const float* C_init = (const float*)d_in[1];
  const float* attl_W = (const float*)d_in[2];
  const float* attl_b = (const float*)d_in[3];
  const float* attc_W = (const float*)d_in[4];
  const float* attc_b = (const float*)d_in[5];
  const float* lit_W  = (const float*)d_in[6];
  const float* lit_b  = (const float*)d_in[7];
  const float* cls_W  = (const float*)d_in[8];
  const float* cls_b  = (const float*)d_in[9];
  const float* ln_g   = (const float*)d_in[10];
  const float* ln_b   = (const float*)d_in[11];
  const float* outW1  = (const float*)d_in[12];
  const float* outb1  = (const float*)d_in[13];
  const float* outW2  = (const float*)d_in[14];
  const float* outb2  = (const float*)d_in[15];
  const float* outW3  = (const float*)d_in[16];
  const float* outb3  = (const float*)d_in[17];
  const int* lit_idx  = (const int*)d_in[18];
  const int* clauses  = (const int*)d_in[20];

  const int nv = out_size - 1;        // 20000
  const int NL = 2 * nv;              // 40000
  const int E  = in_sizes[18];        // 252000
  const int NC = in_sizes[20] / 3;    // 84000

  char* wp = (char*)d_ws;
  auto alloc = [&](size_t bytes) -> char* {
    char* p = wp; wp += (bytes + 255) & ~(size_t)255; return p;
  };

  short* TW     = (short*)alloc(sizeof(short) * (size_t)(12 * 65536 + 2 * 262144));
  short* T_attc = TW;
  short* T_cls  = TW + 3 * 65536;
  short* T_attl = TW + 6 * 65536;
  short* T_lit  = TW + 9 * 65536;
  short* T_o1   = TW + 12 * 65536;
  short* T_o2   = T_o1 + 262144;

  size_t PE = (size_t)NC * 256;
  if ((size_t)nv * 512 > PE) PE = (size_t)nv * 512;
  short* P0   = (short*)alloc(2 * PE);
  short* P1   = (short*)alloc(2 * PE);   // also holds KV_l [NL][512]
  short* c_st = (short*)alloc(2 * (size_t)NC * 256);
  short* l_st = (short*)alloc(2 * (size_t)NL * 256);
  short* c1b  = (short*)alloc(2 * (size_t)NC * 256);
  short* l1b  = (short*)alloc(2 * (size_t)NL * 256);   // also holds vote h1 [nv][512]
  float* lg8  = (float*)alloc(4 * (size_t)nv * 8);
  float* total = (float*)alloc(256);
  int* cnt   = (int*)alloc(4 * (size_t)NL);
  int* cur   = (int*)alloc(4 * (size_t)NL);
  int* offs  = (int*)alloc(4 * (size_t)(NL + 1));
  int* excl  = (int*)alloc(4 * (size_t)NL);
  int* bsum  = (int*)alloc(4 * 256);
  int* elist = (int*)alloc(4 * (size_t)E);

  if ((size_t)(wp - (char*)d_ws) > ws_size) return;

  zero_i32_k<<<dim3((NL + 255) / 256), dim3(256), 0, stream>>>(cnt, NL);
  zero_i32_k<<<dim3((NL + 255) / 256), dim3(256), 0, stream>>>(cur, NL);
  zero_f32_k<<<dim3(1), dim3(256), 0, stream>>>(total, 1);

  auto tps = [&](const float* src, short* dst, int Kd, int Nd) {
    int tot = Kd * Nd;
    transpose_k<<<dim3((tot + 255) / 256), dim3(256), 0, stream>>>(src, dst, Kd, Nd);
  };
  for (int j = 0; j < 3; ++j) {
    tps(attc_W + j * 65536, T_attc + j * 65536, 256, 256);
    tps(cls_W  + j * 65536, T_cls  + j * 65536, 256, 256);
    tps(attl_W + j * 65536, T_attl + j * 65536, 256, 256);
    tps(lit_W  + j * 65536, T_lit  + j * 65536, 256, 256);
  }
  tps(outW1, T_o1, 512, 512);
  tps(outW2, T_o2, 512, 512);

  int nb = (NL + 255) / 256;
  hist_k<<<dim3((E + 255) / 256), dim3(256), 0, stream>>>(lit_idx, cnt, E);
  scan1_k<<<dim3(nb), dim3(256), 0, stream>>>(cnt, excl, bsum, NL);
  scan2_k<<<dim3(1), dim3(256), 0, stream>>>(bsum, nb);
  scan3_k<<<dim3(nb), dim3(256), 0, stream>>>(excl, bsum, offs, NL, E);
  fill_k<<<dim3((E + 255) / 256), dim3(256), 0, stream>>>(lit_idx, offs, cur, elist, E);

  init_state_k<<<dim3(((NC * 256) + 255) / 256), dim3(256), 0, stream>>>(C_init, c_st, NC);
  init_state_k<<<dim3(((NL * 256) + 255) / 256), dim3(256), 0, stream>>>(L_init, l_st, NL);

  dim3 gC((NC + 3) / 4), gL((NL + 3) / 4);

  const int mtC = (NC + 127) / 128;   // 657
  const int mtL = (NL + 127) / 128;   // 313
  const int mtV = (nv + 127) / 128;   // 157

  for (int rd = 0; rd < 32; ++rd) {
    int vblk = (rd > 0) ? mtV * 4 : 0;
    // ---- launch A: Qc(r), KVl(r), vote1(r-1) -> h1 in l1b
    {
      Seg sQc  { c_st, T_attc,         attc_b,       P0, nullptr, NC, mtC * 2, 2, 256, 256, 0, 0, 0, 0 };
      Seg sKVl { l_st, T_attc + 65536, attc_b + 256, P1, nullptr, NL, mtL * 4, 4, 512, 256, 0, 0, 0, 0 };
      Seg sV1  { l_st, T_o1,           outb1,        l1b, nullptr, nv, vblk,   4, 512, 512, 1, 1, 0, nv };
      gemm_multi3_k<<<dim3(sQc.nblk + sKVl.nblk + sV1.nblk), dim3(256), 0, stream>>>(
          sQc, sKVl, sV1, nullptr, nullptr);
    }
    clause_attn_k<<<gC, dim3(256), 0, stream>>>(P0, P1, lit_idx, c_st,
                                                ln_g + 0, ln_b + 0, c1b, NC);     // c1
    mlp3ln_k<<<dim3((NC + 63) / 64), dim3(512), 0, stream>>>(
        c1b, T_cls, T_cls + 65536, T_cls + 2 * 65536, cls_b, cls_b + 256, cls_b + 512,
        ln_g + 3*256, ln_b + 3*256, c_st, NC);                                    // c2

    // ---- launch B: Ql(r), Kc|Vc(r), vote2(r-1) logits -> lg8
    {
      Seg sQl  { l_st, T_attl,         attl_b,       P0, nullptr, NL, mtL * 2, 2, 256, 256, 0, 0, 0, 0 };
      Seg sKVc { c_st, T_attl + 65536, attl_b + 256, P1, c1b,     NC, mtC * 4, 4, 256, 256, 0, 0, 0, 0 };
      Seg sV2  { l1b,  T_o2,           outb2,        nullptr, nullptr, nv, vblk, 4, 512, 512, 1, 0, 1, 0 };
      gemm_multi3_k<<<dim3(sQl.nblk + sKVc.nblk + sV2.nblk), dim3(256), 0, stream>>>(
          sQl, sKVc, sV2, outW3, lg8);
    }
    if (rd > 0)
      loss_k<<<dim3((NC + 255) / 256), dim3(256), 0, stream>>>(clauses, lg8, outb3, total, NC);

    lit_attn_k<<<gL, dim3(256), 0, stream>>>(P0, P1, c1b, offs, elist, l_st,
                                             ln_g + 256, ln_b + 256, l1b, NL, nv); // l1
    mlp3ln_k<<<dim3((NL + 63) / 64), dim3(512), 0, stream>>>(
        l1b, T_lit, T_lit + 65536, T_lit + 2 * 65536, lit_b, lit_b + 256, lit_b + 512,
        ln_g + 2*256, ln_b + 2*256, l_st, NL);                                    // l2
  }

  // ---- drain: vote chain for round 31
  {
    dim3 grd(mtV * 4);
    gemm_lds_k<1,512,512,1,0,4><<<grd, dim3(256), 0, stream>>>(l_st, T_o1, outb1, l1b, nv, nv, nullptr, nullptr);
    gemm_lds_k<1,512,512,0,1,4><<<grd, dim3(256), 0, stream>>>(l1b, T_o2, outb2, nullptr, nv, 0, outW3, lg8);
    loss_k<<<dim3((NC + 255) / 256), dim3(256), 0, stream>>>(clauses, lg8, outb3, total, NC);
  }

  writeout_k<<<dim3((nv + 256) / 256), dim3(256), 0, stream>>>(lg8, outb3, total, (float*)d_out, nv);
}

// Round 23
// 10604.915 us; speedup vs baseline: 1.1767x; 1.1767x over previous
//
#include <hip/hip_runtime.h>
#include <cstdint>
#include <cstddef>

typedef float f32x4 __attribute__((ext_vector_type(4)));
typedef __bf16 bfv8 __attribute__((ext_vector_type(8)));
typedef short sv4 __attribute__((ext_vector_type(4)));
typedef short sv8 __attribute__((ext_vector_type(8)));

__device__ __forceinline__ float b2f(short u) {
  union { unsigned int i; float f; } x;
  x.i = ((unsigned int)(unsigned short)u) << 16;
  return x.f;
}
__device__ __forceinline__ short f2b(float f) {
  union { float f; unsigned int i; } x; x.f = f;
  unsigned int r = x.i + 0x7fffu + ((x.i >> 16) & 1u);
  return (short)(unsigned short)(r >> 16);
}
__device__ __forceinline__ float wredsum(float v) {
#pragma unroll
  for (int m = 32; m >= 1; m >>= 1) v += __shfl_xor(v, m);
  return v;
}
__device__ __forceinline__ float softplus_f(float x) {
  return fmaxf(x, 0.f) + log1pf(expf(-fabsf(x)));
}

// ================ narrow LDS GEMM (r5/r7 proven) — drain votes ==============
template<int RELU, int KC, int NOUT, int SPLITA, int LOGITS, int NY>
__global__ __launch_bounds__(256)
void gemm_lds_k(const short* __restrict__ A, const short* __restrict__ BT,
                const float* __restrict__ bias, short* __restrict__ Cb,
                int M, int nvoff, const float* __restrict__ w3,
                float* __restrict__ lgout) {
  __shared__ char smem[32768];
  const int t = threadIdx.x;
  const int lane = t & 63;
  const int wid = t >> 6;
  const int wr = wid >> 1, wc = wid & 1;
  const int lr = lane & 15, lk = lane >> 4;

  constexpr int G = 8 * NY;
  int id = blockIdx.x;
  int NX = (int)gridDim.x / NY;
  int nxf = NX & ~7;
  int nfull_ids = nxf * NY;
  int bx, by;
  if (id < nfull_ids) {
    int g = id / G;
    int r = id - g * G;
    bx = g * 8 + (r & 7);
    by = r >> 3;
  } else {
    int rem = id - nfull_ids;
    int w = NX - nxf;
    bx = nxf + rem % w;
    by = rem / w;
  }
  const int m0 = bx * 128;
  const int n0 = by * 128;

  f32x4 acc[4][4];
#pragma unroll
  for (int i = 0; i < 4; ++i)
#pragma unroll
    for (int j = 0; j < 4; ++j) { acc[i][j][0]=0.f; acc[i][j][1]=0.f; acc[i][j][2]=0.f; acc[i][j][3]=0.f; }

  for (int k0 = 0; k0 < KC; k0 += 64) {
#pragma unroll
    for (int i = 0; i < 4; ++i) {
      int p = t + i * 256;
      int row = p >> 3, chunk = p & 7;
      int kb = (chunk * 16) ^ ((row & 7) << 4);
      {
        int rg = m0 + row; if (rg >= M) rg = M - 1;
        const short* src;
        if (SPLITA) {
          int keff = k0 + (kb >> 1);
          src = (keff < 256) ? (A + (size_t)rg * 256 + keff)
                             : (A + (size_t)(rg + nvoff) * 256 + (keff - 256));
        } else {
          src = A + (size_t)rg * KC + k0 + (kb >> 1);
        }
        int dstb = (wid * 64 + i * 256) * 16;
        __builtin_amdgcn_global_load_lds(
            (const __attribute__((address_space(1))) void*)src,
            (__attribute__((address_space(3))) void*)(smem + dstb), 16, 0, 0);
      }
      {
        const short* src = BT + (size_t)(n0 + row) * KC + k0 + (kb >> 1);
        int dstb = 16384 + (wid * 64 + i * 256) * 16;
        __builtin_amdgcn_global_load_lds(
            (const __attribute__((address_space(1))) void*)src,
            (__attribute__((address_space(3))) void*)(smem + dstb), 16, 0, 0);
      }
    }
    __syncthreads();

#pragma unroll
    for (int kk = 0; kk < 64; kk += 32) {
      bfv8 af[4], bfr[4];
#pragma unroll
      for (int mf = 0; mf < 4; ++mf) {
        int row = wr * 64 + mf * 16 + lr;
        int kb = (kk * 2 + lk * 16) ^ ((row & 7) << 4);
        af[mf] = *(const bfv8*)(smem + row * 128 + kb);
      }
#pragma unroll
      for (int nf = 0; nf < 4; ++nf) {
        int row = wc * 64 + nf * 16 + lr;
        int kb = (kk * 2 + lk * 16) ^ ((row & 7) << 4);
        bfr[nf] = *(const bfv8*)(smem + 16384 + row * 128 + kb);
      }
#pragma unroll
      for (int mf = 0; mf < 4; ++mf)
#pragma unroll
        for (int nf = 0; nf < 4; ++nf)
          acc[mf][nf] = __builtin_amdgcn_mfma_f32_16x16x32_bf16(af[mf], bfr[nf], acc[mf][nf], 0, 0, 0);
    }
    __syncthreads();
  }

  if constexpr (LOGITS) {
#pragma unroll
    for (int mf = 0; mf < 4; ++mf) {
#pragma unroll
      for (int q = 0; q < 4; ++q) {
        float pd = 0.f;
#pragma unroll
        for (int nf = 0; nf < 4; ++nf) {
          int col = n0 + wc * 64 + nf * 16 + lr;
          float v = fmaxf(acc[mf][nf][q] + bias[col], 0.f);
          pd += v * w3[col];
        }
#pragma unroll
        for (int msk = 8; msk >= 1; msk >>= 1) pd += __shfl_xor(pd, msk);
        int row = m0 + wr * 64 + mf * 16 + lk * 4 + q;
        if (lr == 0 && row < M) lgout[(size_t)row * 8 + (n0 >> 7) * 2 + wc] = pd;
      }
    }
  } else {
#pragma unroll
    for (int nf = 0; nf < 4; ++nf) {
      int col = n0 + wc * 64 + nf * 16 + lr;
      float bv = bias[col];
#pragma unroll
      for (int mf = 0; mf < 4; ++mf) {
#pragma unroll
        for (int q = 0; q < 4; ++q) {
          int row = m0 + wr * 64 + mf * 16 + lk * 4 + q;
          if (row < M) {
            float v = acc[mf][nf][q] + bv;
            if (RELU) v = fmaxf(v, 0.f);
            Cb[(size_t)row * NOUT + col] = f2b(v);
          }
        }
      }
    }
  }
}

// ================ 3-segment GEMM (r14 proven loop) + LDS-staged C-writes ====
// Epilogue (r21 proven): stage C-tile in the (dead) 32KB LDS with XOR swizzle,
// then fully-coalesced 16B stores -> kills the measured 1.83x write
// amplification of the scalar-2B-store epilogue.
struct Seg {
  const short* A; const short* BT; const float* bias;
  short* C0; short* C1;
  int M, nblk, ny, cstride, kc;
  int relu, splitA, logits, nvoff;
};

__global__ __launch_bounds__(256)
void gemm_multi3_k(Seg s0, Seg s1, Seg s2,
                   const float* __restrict__ w3, float* __restrict__ lgout) {
  __shared__ char smem[32768];
  const int t = threadIdx.x;
  const int lane = t & 63;
  const int wid = t >> 6;
  const int wr = wid >> 1, wc = wid & 1;
  const int lr = lane & 15, lk = lane >> 4;

  int id = blockIdx.x;
  Seg s;
  if (id < s0.nblk) { s = s0; }
  else if (id < s0.nblk + s1.nblk) { s = s1; id -= s0.nblk; }
  else { s = s2; id -= s0.nblk + s1.nblk; }

  int NX = s.nblk / s.ny;
  int nxf = NX & ~7;
  int nfull = nxf * s.ny;
  int bx, by;
  if (id < nfull) {
    int G = 8 * s.ny;
    int g = id / G;
    int r = id - g * G;
    bx = g * 8 + (r & 7);
    by = r >> 3;
  } else {
    int rem = id - nfull;
    int w = NX - nxf;
    bx = nxf + rem % w;
    by = rem / w;
  }
  const int m0 = bx * 128;
  const int nrow0 = by * 128;

  f32x4 acc[4][4];
#pragma unroll
  for (int i = 0; i < 4; ++i)
#pragma unroll
    for (int j = 0; j < 4; ++j) { acc[i][j][0]=0.f; acc[i][j][1]=0.f; acc[i][j][2]=0.f; acc[i][j][3]=0.f; }

  for (int k0 = 0; k0 < s.kc; k0 += 64) {
#pragma unroll
    for (int i = 0; i < 4; ++i) {
      int p = t + i * 256;
      int row = p >> 3, chunk = p & 7;
      int kb = (chunk * 16) ^ ((row & 7) << 4);
      {
        int rg = m0 + row; if (rg >= s.M) rg = s.M - 1;
        const short* src;
        if (s.splitA) {
          int keff = k0 + (kb >> 1);
          src = (keff < 256) ? (s.A + (size_t)rg * 256 + keff)
                             : (s.A + (size_t)(rg + s.nvoff) * 256 + (keff - 256));
        } else {
          src = s.A + (size_t)rg * s.kc + k0 + (kb >> 1);
        }
        int dstb = (wid * 64 + i * 256) * 16;
        __builtin_amdgcn_global_load_lds(
            (const __attribute__((address_space(1))) void*)src,
            (__attribute__((address_space(3))) void*)(smem + dstb), 16, 0, 0);
      }
      {
        const short* src = s.BT + (size_t)(nrow0 + row) * s.kc + k0 + (kb >> 1);
        int dstb = 16384 + (wid * 64 + i * 256) * 16;
        __builtin_amdgcn_global_load_lds(
            (const __attribute__((address_space(1))) void*)src,
            (__attribute__((address_space(3))) void*)(smem + dstb), 16, 0, 0);
      }
    }
    __syncthreads();

#pragma unroll
    for (int kk = 0; kk < 64; kk += 32) {
      bfv8 af[4], bfr[4];
#pragma unroll
      for (int mf = 0; mf < 4; ++mf) {
        int row = wr * 64 + mf * 16 + lr;
        int kb = (kk * 2 + lk * 16) ^ ((row & 7) << 4);
        af[mf] = *(const bfv8*)(smem + row * 128 + kb);
      }
#pragma unroll
      for (int nf = 0; nf < 4; ++nf) {
        int row = wc * 64 + nf * 16 + lr;
        int kb = (kk * 2 + lk * 16) ^ ((row & 7) << 4);
        bfr[nf] = *(const bfv8*)(smem + 16384 + row * 128 + kb);
      }
#pragma unroll
      for (int mf = 0; mf < 4; ++mf)
#pragma unroll
        for (int nf = 0; nf < 4; ++nf)
          acc[mf][nf] = __builtin_amdgcn_mfma_f32_16x16x32_bf16(af[mf], bfr[nf], acc[mf][nf], 0, 0, 0);
    }
    __syncthreads();
  }

  if (s.logits) {
#pragma unroll
    for (int mf = 0; mf < 4; ++mf) {
#pragma unroll
      for (int q = 0; q < 4; ++q) {
        float pd = 0.f;
#pragma unroll
        for (int nf = 0; nf < 4; ++nf) {
          int col = nrow0 + wc * 64 + nf * 16 + lr;
          float v = fmaxf(acc[mf][nf][q] + s.bias[col], 0.f);
          pd += v * w3[col];
        }
#pragma unroll
        for (int msk = 8; msk >= 1; msk >>= 1) pd += __shfl_xor(pd, msk);
        int row = m0 + wr * 64 + mf * 16 + lk * 4 + q;
        if (lr == 0 && row < s.M) lgout[(size_t)row * 8 + by * 2 + wc] = pd;
      }
    }
  } else {
    short* Cb; int colb;
    if (s.C1) {
      int h = s.ny >> 1;
      Cb = (by < h) ? s.C0 : s.C1;
      colb = (by % h) * 128;
    } else {
      Cb = s.C0;
      colb = by * 128;
    }
    // stage C tile (128x128 bf16 = 32KB) into LDS, XOR-swizzled per row
#pragma unroll
    for (int nf = 0; nf < 4; ++nf) {
      int cl = wc * 64 + nf * 16 + lr;
      float bv = s.bias[nrow0 + cl];
#pragma unroll
      for (int mf = 0; mf < 4; ++mf) {
#pragma unroll
        for (int q = 0; q < 4; ++q) {
          int rloc = wr * 64 + mf * 16 + lk * 4 + q;
          float v = acc[mf][nf][q] + bv;
          if (s.relu) v = fmaxf(v, 0.f);
          int byte = rloc * 256 + ((cl * 2) ^ ((rloc & 7) << 4));
          *(short*)(smem + byte) = f2b(v);
        }
      }
    }
    __syncthreads();
    // coalesced 16B stores: 16 lanes cover a full 256B row (chunk-permuted)
#pragma unroll
    for (int i = 0; i < 8; ++i) {
      int p = t + i * 256;
      int rloc = p >> 4, chunk = p & 15;
      int grow = m0 + rloc;
      if (grow < s.M) {
        int gcol = colb + ((chunk * 8) ^ ((rloc & 7) << 3));   // in shorts
        *(sv8*)(Cb + (size_t)grow * s.cstride + gcol) =
            *(const sv8*)(smem + rloc * 256 + chunk * 16);
      }
    }
  }
}

// ================ fused 3-layer MLP + residual + LN, 52KB LDS (r16 proven) ==
// out = LN(A + relu(relu(A@W1+b1)@W2+b2)@W3 + b3) ; tile 64 rows, 8 waves.
// BK=32. LDS: Astage/LN [0,4K) Wstage [4K,20K) h [20K,52K).
__global__ __launch_bounds__(512)
void mlp3ln_k(const short* __restrict__ A, const short* __restrict__ W1T,
              const short* __restrict__ W2T, const short* __restrict__ W3T,
              const float* __restrict__ b1, const float* __restrict__ b2,
              const float* __restrict__ b3, const float* __restrict__ g,
              const float* __restrict__ be, short* __restrict__ outp, int M) {
  __shared__ char smem[53248];
  const int t = threadIdx.x;
  const int lane = t & 63;
  const int wid = t >> 6;               // 0..7
  const int wr = wid >> 2, wc = wid & 3;
  const int lr = lane & 15, lk = lane >> 4;
  const int m0 = blockIdx.x * 64;

  float* lnS = (float*)smem;            // [4][64], overlaps dead A-stage region
  float* lnQ = (float*)(smem + 1024);

  // ---- phase 1: h1 = relu(A @ W1 + b1) -> LDS [20K,52K)
  f32x4 acc[2][4];
#pragma unroll
  for (int i = 0; i < 2; ++i)
#pragma unroll
    for (int j = 0; j < 4; ++j) { acc[i][j][0]=0.f; acc[i][j][1]=0.f; acc[i][j][2]=0.f; acc[i][j][3]=0.f; }

  for (int k0 = 0; k0 < 256; k0 += 32) {
    if (wid < 4) {                        // A chunk [64 rows][32 k]: 256 granules
      int p = t;                          // 0..255
      int row = p >> 2, chunk = p & 3;
      int kb = (chunk * 16) ^ ((row & 3) << 4);
      int rg = m0 + row; if (rg >= M) rg = M - 1;
      const short* src = A + (size_t)rg * 256 + k0 + (kb >> 1);
      __builtin_amdgcn_global_load_lds(
          (const __attribute__((address_space(1))) void*)src,
          (__attribute__((address_space(3))) void*)(smem + wid * 1024), 16, 0, 0);
    }
#pragma unroll
    for (int i = 0; i < 2; ++i) {         // W1 chunk [256 cols][32 k]: 1024 granules
      int p = t + i * 512;
      int row = p >> 2, chunk = p & 3;
      int kb = (chunk * 16) ^ ((row & 3) << 4);
      const short* src = W1T + (size_t)row * 256 + k0 + (kb >> 1);
      __builtin_amdgcn_global_load_lds(
          (const __attribute__((address_space(1))) void*)src,
          (__attribute__((address_space(3))) void*)(smem + 4096 + (wid * 64 + i * 512) * 16), 16, 0, 0);
    }
    __syncthreads();

    bfv8 af[2], bfr[4];
#pragma unroll
    for (int mf = 0; mf < 2; ++mf) {
      int row = wr * 32 + mf * 16 + lr;
      int kb = (lk * 16) ^ ((row & 3) << 4);
      af[mf] = *(const bfv8*)(smem + row * 64 + kb);
    }
#pragma unroll
    for (int nf = 0; nf < 4; ++nf) {
      int row = wc * 64 + nf * 16 + lr;
      int kb = (lk * 16) ^ ((row & 3) << 4);
      bfr[nf] = *(const bfv8*)(smem + 4096 + row * 64 + kb);
    }
#pragma unroll
    for (int mf = 0; mf < 2; ++mf)
#pragma unroll
      for (int nf = 0; nf < 4; ++nf)
        acc[mf][nf] = __builtin_amdgcn_mfma_f32_16x16x32_bf16(af[mf], bfr[nf], acc[mf][nf], 0, 0, 0);
    __syncthreads();
  }

  // write h1 into LDS [20K,52K): row*512 + ((col*2) ^ ((row&7)<<4))
#pragma unroll
  for (int mf = 0; mf < 2; ++mf) {
#pragma unroll
    for (int nf = 0; nf < 4; ++nf) {
      int col = wc * 64 + nf * 16 + lr;
      float bv = b1[col];
#pragma unroll
      for (int q = 0; q < 4; ++q) {
        int row = wr * 32 + mf * 16 + lk * 4 + q;
        float v = fmaxf(acc[mf][nf][q] + bv, 0.f);
        int byte = 20480 + row * 512 + ((col * 2) ^ ((row & 7) << 4));
        *(short*)(smem + byte) = f2b(v);
      }
    }
  }

  // ---- phase 2: acc2 = h1 @ W2
  f32x4 acc2[2][4];
#pragma unroll
  for (int i = 0; i < 2; ++i)
#pragma unroll
    for (int j = 0; j < 4; ++j) { acc2[i][j][0]=0.f; acc2[i][j][1]=0.f; acc2[i][j][2]=0.f; acc2[i][j][3]=0.f; }

  for (int k0 = 0; k0 < 256; k0 += 32) {
#pragma unroll
    for (int i = 0; i < 2; ++i) {
      int p = t + i * 512;
      int row = p >> 2, chunk = p & 3;
      int kb = (chunk * 16) ^ ((row & 3) << 4);
      const short* src = W2T + (size_t)row * 256 + k0 + (kb >> 1);
      __builtin_amdgcn_global_load_lds(
          (const __attribute__((address_space(1))) void*)src,
          (__attribute__((address_space(3))) void*)(smem + 4096 + (wid * 64 + i * 512) * 16), 16, 0, 0);
    }
    __syncthreads();   // h1 writes (first iter) + W2 stage visible

    bfv8 af[2], bfr[4];
#pragma unroll
    for (int mf = 0; mf < 2; ++mf) {
      int row = wr * 32 + mf * 16 + lr;
      int kb = (k0 * 2 + lk * 16) ^ ((row & 7) << 4);
      af[mf] = *(const bfv8*)(smem + 20480 + row * 512 + kb);
    }
#pragma unroll
    for (int nf = 0; nf < 4; ++nf) {
      int row = wc * 64 + nf * 16 + lr;
      int kb = (lk * 16) ^ ((row & 3) << 4);
      bfr[nf] = *(const bfv8*)(smem + 4096 + row * 64 + kb);
    }
#pragma unroll
    for (int mf = 0; mf < 2; ++mf)
#pragma unroll
      for (int nf = 0; nf < 4; ++nf)
        acc2[mf][nf] = __builtin_amdgcn_mfma_f32_16x16x32_bf16(af[mf], bfr[nf], acc2[mf][nf], 0, 0, 0);
    __syncthreads();   // all h1 reads for this chunk done
  }

  // h2 = relu(acc2 + b2) overwrites the h-buffer (h1 dead)
#pragma unroll
  for (int mf = 0; mf < 2; ++mf) {
#pragma unroll
    for (int nf = 0; nf < 4; ++nf) {
      int col = wc * 64 + nf * 16 + lr;
      float bv = b2[col];
#pragma unroll
      for (int q = 0; q < 4; ++q) {
        int row = wr * 32 + mf * 16 + lk * 4 + q;
        float v = fmaxf(acc2[mf][nf][q] + bv, 0.f);
        int byte = 20480 + row * 512 + ((col * 2) ^ ((row & 7) << 4));
        *(short*)(smem + byte) = f2b(v);
      }
    }
  }

  // ---- phase 3: acc3 = h2 @ W3 ; epilogue residual + LN
  f32x4 acc3[2][4];
#pragma unroll
  for (int i = 0; i < 2; ++i)
#pragma unroll
    for (int j = 0; j < 4; ++j) { acc3[i][j][0]=0.f; acc3[i][j][1]=0.f; acc3[i][j][2]=0.f; acc3[i][j][3]=0.f; }

  for (int k0 = 0; k0 < 256; k0 += 32) {
#pragma unroll
    for (int i = 0; i < 2; ++i) {
      int p = t + i * 512;
      int row = p >> 2, chunk = p & 3;
      int kb = (chunk * 16) ^ ((row & 3) << 4);
      const short* src = W3T + (size_t)row * 256 + k0 + (kb >> 1);
      __builtin_amdgcn_global_load_lds(
          (const __attribute__((address_space(1))) void*)src,
          (__attribute__((address_space(3))) void*)(smem + 4096 + (wid * 64 + i * 512) * 16), 16, 0, 0);
    }
    __syncthreads();   // h2 writes (first iter) + W3 stage visible

    bfv8 af[2], bfr[4];
#pragma unroll
    for (int mf = 0; mf < 2; ++mf) {
      int row = wr * 32 + mf * 16 + lr;
      int kb = (k0 * 2 + lk * 16) ^ ((row & 7) << 4);
      af[mf] = *(const bfv8*)(smem + 20480 + row * 512 + kb);
    }
#pragma unroll
    for (int nf = 0; nf < 4; ++nf) {
      int row = wc * 64 + nf * 16 + lr;
      int kb = (lk * 16) ^ ((row & 3) << 4);
      bfr[nf] = *(const bfv8*)(smem + 4096 + row * 64 + kb);
    }
#pragma unroll
    for (int mf = 0; mf < 2; ++mf)
#pragma unroll
      for (int nf = 0; nf < 4; ++nf)
        acc3[mf][nf] = __builtin_amdgcn_mfma_f32_16x16x32_bf16(af[mf], bfr[nf], acc3[mf][nf], 0, 0, 0);
    __syncthreads();
  }

  // epilogue: + b3 + residual(A) -> row LayerNorm -> out
#pragma unroll
  for (int nf = 0; nf < 4; ++nf) {
    int col = wc * 64 + nf * 16 + lr;
    float bv = b3[col];
#pragma unroll
    for (int mf = 0; mf < 2; ++mf) {
#pragma unroll
      for (int q = 0; q < 4; ++q) {
        int row = m0 + wr * 32 + mf * 16 + lk * 4 + q;
        int rr = row < M ? row : M - 1;
        acc3[mf][nf][q] += bv + b2f(A[(size_t)rr * 256 + col]);
      }
    }
  }
#pragma unroll
  for (int mf = 0; mf < 2; ++mf) {
#pragma unroll
    for (int q = 0; q < 4; ++q) {
      float s  = acc3[mf][0][q] + acc3[mf][1][q] + acc3[mf][2][q] + acc3[mf][3][q];
      float ss = acc3[mf][0][q]*acc3[mf][0][q] + acc3[mf][1][q]*acc3[mf][1][q]
               + acc3[mf][2][q]*acc3[mf][2][q] + acc3[mf][3][q]*acc3[mf][3][q];
#pragma unroll
      for (int msk = 8; msk >= 1; msk >>= 1) {
        s  += __shfl_xor(s, msk);
        ss += __shfl_xor(ss, msk);
      }
      if (lr == 0) {
        int rloc = wr * 32 + mf * 16 + lk * 4 + q;
        lnS[wc * 64 + rloc] = s;
        lnQ[wc * 64 + rloc] = ss;
      }
    }
  }
  __syncthreads();
#pragma unroll
  for (int mf = 0; mf < 2; ++mf) {
#pragma unroll
    for (int q = 0; q < 4; ++q) {
      int rloc = wr * 32 + mf * 16 + lk * 4 + q;
      float S  = lnS[rloc] + lnS[64 + rloc] + lnS[128 + rloc] + lnS[192 + rloc];
      float SQ = lnQ[rloc] + lnQ[64 + rloc] + lnQ[128 + rloc] + lnQ[192 + rloc];
      float mu = S * (1.f/256.f);
      float var = SQ * (1.f/256.f) - mu * mu;
      float rs = rsqrtf(fmaxf(var, 0.f) + 1e-3f);
      int row = m0 + rloc;
      if (row < M) {
#pragma unroll
        for (int nf = 0; nf < 4; ++nf) {
          int col = wc * 64 + nf * 16 + lr;
          float y = (acc3[mf][nf][q] - mu) * rs * g[col] + be[col];
          outp[(size_t)row * 256 + col] = f2b(y);
        }
      }
    }
  }
}

// ---------------- transpose W[K,N] (f32) -> WT[N,K] (bf16)
__global__ void transpose_k(const float* __restrict__ W, short* __restrict__ WT, int Kd, int Nd) {
  int idx = blockIdx.x * 256 + threadIdx.x;
  if (idx >= Kd * Nd) return;
  int k = idx / Nd, n = idx - k * Nd;
  WT[(size_t)n * Kd + k] = f2b(W[idx]);
}

__global__ void init_state_k(const float* __restrict__ initrow, short* __restrict__ st, int rows) {
  int idx = blockIdx.x * 256 + threadIdx.x;
  if (idx >= rows * 256) return;
  st[idx] = f2b(initrow[idx & 255] * 0.0625f);
}

__global__ void zero_i32_k(int* __restrict__ p, int n) {
  int i = blockIdx.x * 256 + threadIdx.x;
  if (i < n) p[i] = 0;
}
__global__ void zero_f32_k(float* __restrict__ p, int n) {
  int i = blockIdx.x * 256 + threadIdx.x;
  if (i < n) p[i] = 0.f;
}

// ---------------- clause attention (r8-proven math, KV interleaved)
__global__ void clause_attn_k(const short* __restrict__ Q, const short* __restrict__ KV,
                              const int* __restrict__ lit_idx,
                              const short* __restrict__ cin, const float* __restrict__ g,
                              const float* __restrict__ be, short* __restrict__ ob, int NC) {
  int i = blockIdx.x * 4 + (threadIdx.x >> 6);
  if (i >= NC) return;
  int lane = threadIdx.x & 63;
  int d0 = lane * 4;
  sv4 qv = *(const sv4*)(Q + (size_t)i * 256 + d0);
  int L0 = lit_idx[3*i], L1 = lit_idx[3*i+1], L2 = lit_idx[3*i+2];
  float s0, s1, s2;
  {
    sv4 k0 = *(const sv4*)(KV + (size_t)L0 * 512 + d0);
    sv4 k1 = *(const sv4*)(KV + (size_t)L1 * 512 + d0);
    sv4 k2 = *(const sv4*)(KV + (size_t)L2 * 512 + d0);
    float d0s = 0.f, d1s = 0.f, d2s = 0.f;
#pragma unroll
    for (int t = 0; t < 4; ++t) {
      float qf = b2f(qv[t]);
      d0s += qf * b2f(k0[t]);
      d1s += qf * b2f(k1[t]);
      d2s += qf * b2f(k2[t]);
    }
    s0 = wredsum(d0s) * 0.0625f;
    s1 = wredsum(d1s) * 0.0625f;
    s2 = wredsum(d2s) * 0.0625f;
  }
  float m = fmaxf(s0, fmaxf(s1, s2));
  float e0 = expf(s0 - m), e1 = expf(s1 - m), e2 = expf(s2 - m);
  float inv = 1.f / (e0 + e1 + e2 + 1e-9f);
  float a0 = e0 * inv, a1 = e1 * inv, a2 = e2 * inv;
  sv4 v0 = *(const sv4*)(KV + (size_t)L0 * 512 + 256 + d0);
  sv4 v1 = *(const sv4*)(KV + (size_t)L1 * 512 + 256 + d0);
  sv4 v2 = *(const sv4*)(KV + (size_t)L2 * 512 + 256 + d0);
  sv4 cv = *(const sv4*)(cin + (size_t)i * 256 + d0);
  float x[4];
#pragma unroll
  for (int t = 0; t < 4; ++t)
    x[t] = b2f(cv[t]) + a0*b2f(v0[t]) + a1*b2f(v1[t]) + a2*b2f(v2[t]);
  float s = x[0]+x[1]+x[2]+x[3];
  float ss = x[0]*x[0]+x[1]*x[1]+x[2]*x[2]+x[3]*x[3];
  s = wredsum(s); ss = wredsum(ss);
  float mu = s * (1.f/256.f);
  float var = ss * (1.f/256.f) - mu*mu;
  float rs = rsqrtf(fmaxf(var, 0.f) + 1e-3f);
  f32x4 gv = *(const f32x4*)(g + d0);
  f32x4 bv = *(const f32x4*)(be + d0);
  sv4 yb;
#pragma unroll
  for (int t = 0; t < 4; ++t) yb[t] = f2b((x[t]-mu)*rs*gv[t] + bv[t]);
  *(sv4*)(ob + (size_t)i*256 + d0) = yb;
}

// ---------------- literal attention (r11-proven, 4-edge batch)
__global__ void lit_attn_k(const short* __restrict__ Q, const short* __restrict__ K,
                           const short* __restrict__ V, const int* __restrict__ offs,
                           const int* __restrict__ elist, const short* __restrict__ lin,
                           const float* __restrict__ g, const float* __restrict__ be,
                           short* __restrict__ ob, int NLIT, int nv) {
  int q = blockIdx.x * 4 + (threadIdx.x >> 6);
  if (q >= NLIT) return;
  int lane = threadIdx.x & 63;
  int o0 = offs[q], o1 = offs[q+1];
  int r = (q < nv) ? q + nv : q - nv;
  int d0 = lane * 4;
  sv4 qv = *(const sv4*)(Q + (size_t)q * 256 + d0);
  float m = -1e30f, ssum = 0.f;
  float acc[4] = {0.f, 0.f, 0.f, 0.f};
  for (int j = o0; j < o1; j += 4) {
    int nb = o1 - j; if (nb > 4) nb = 4;
    sv4 kr0, kr1, kr2, kr3, vr0, vr1, vr2, vr3;
    float dd0, dd1, dd2, dd3;
    {
      int e0i = elist[j];
      int e1i = elist[(1 < nb) ? j + 1 : j];
      int e2i = elist[(2 < nb) ? j + 2 : j];
      int e3i = elist[(3 < nb) ? j + 3 : j];
      size_t c0 = (size_t)(e0i / 3) * 256, c1 = (size_t)(e1i / 3) * 256;
      size_t c2 = (size_t)(e2i / 3) * 256, c3 = (size_t)(e3i / 3) * 256;
      kr0 = *(const sv4*)(K + c0 + d0); vr0 = *(const sv4*)(V + c0 + d0);
      kr1 = *(const sv4*)(K + c1 + d0); vr1 = *(const sv4*)(V + c1 + d0);
      kr2 = *(const sv4*)(K + c2 + d0); vr2 = *(const sv4*)(V + c2 + d0);
      kr3 = *(const sv4*)(K + c3 + d0); vr3 = *(const sv4*)(V + c3 + d0);
    }
    dd0 = dd1 = dd2 = dd3 = 0.f;
#pragma unroll
    for (int t = 0; t < 4; ++t) {
      float qf = b2f(qv[t]);
      dd0 += qf * b2f(kr0[t]);
      dd1 += qf * b2f(kr1[t]);
      dd2 += qf * b2f(kr2[t]);
      dd3 += qf * b2f(kr3[t]);
    }
#pragma unroll
    for (int msk = 32; msk >= 1; msk >>= 1) {
      dd0 += __shfl_xor(dd0, msk);
      dd1 += __shfl_xor(dd1, msk);
      dd2 += __shfl_xor(dd2, msk);
      dd3 += __shfl_xor(dd3, msk);
    }
    float ds[4] = {dd0, dd1, dd2, dd3};
    sv4 vrs[4] = {vr0, vr1, vr2, vr3};
#pragma unroll
    for (int s = 0; s < 4; ++s) {
      if (s < nb) {
        float d = ds[s] * 0.0625f;
        float nm = fmaxf(m, d);
        float rm = expf(m - nm);
        float w  = expf(d - nm);
        ssum = ssum * rm + w;
#pragma unroll
        for (int t = 0; t < 4; ++t) acc[t] = acc[t] * rm + w * b2f(vrs[s][t]);
        m = nm;
      }
    }
  }
  float winv = (o1 > o0) ? 1.f / (ssum + 1e-9f) : 0.f;
  sv4 lv = *(const sv4*)(lin + (size_t)r * 256 + d0);
  float x[4];
#pragma unroll
  for (int t = 0; t < 4; ++t) x[t] = b2f(lv[t]) + acc[t] * winv;
  float s = x[0]+x[1]+x[2]+x[3];
  float ss = x[0]*x[0]+x[1]*x[1]+x[2]*x[2]+x[3]*x[3];
  s = wredsum(s); ss = wredsum(ss);
  float mu = s * (1.f/256.f);
  float var = ss * (1.f/256.f) - mu*mu;
  float rs = rsqrtf(fmaxf(var, 0.f) + 1e-3f);
  f32x4 gv = *(const f32x4*)(g + d0);
  f32x4 bv = *(const f32x4*)(be + d0);
  sv4 yb;
#pragma unroll
  for (int t = 0; t < 4; ++t) yb[t] = f2b((x[t]-mu)*rs*gv[t] + bv[t]);
  *(sv4*)(ob + (size_t)r*256 + d0) = yb;
}

// ---------------- loss (lg8: 8 partials/variable, + b3)
__global__ void loss_k(const int* __restrict__ clauses, const float* __restrict__ lg8,
                       const float* __restrict__ b3p, float* __restrict__ total, int NC) {
  __shared__ float red[256];
  int i = blockIdx.x * 256 + threadIdx.x;
  float acc = 0.f;
  if (i < NC) {
    float b3v = b3p[0];
    float cs = 0.f;
#pragma unroll
    for (int j = 0; j < 3; ++j) {
      int lit = clauses[3*i + j];
      int v = (lit > 0 ? lit : -lit) - 1;
      float sg = (lit > 0) ? 1.f : -1.f;
      f32x4 a = *(const f32x4*)(lg8 + (size_t)v * 8);
      f32x4 b = *(const f32x4*)(lg8 + (size_t)v * 8 + 4);
      float lv = ((a[0]+a[1])+(a[2]+a[3])) + ((b[0]+b[1])+(b[2]+b[3])) + b3v;
      cs += softplus_f(lv * sg);
    }
    float t = softplus_f(-cs);
    acc = t * t;
  }
  red[threadIdx.x] = acc;
  __syncthreads();
  for (int s = 128; s > 0; s >>= 1) {
    if (threadIdx.x < s) red[threadIdx.x] += red[threadIdx.x + s];
    __syncthreads();
  }
  if (threadIdx.x == 0) atomicAdd(total, red[0]);
}

__global__ void writeout_k(const float* __restrict__ lg8, const float* __restrict__ b3p,
                           const float* __restrict__ total, float* __restrict__ out, int nv) {
  int i = blockIdx.x * 256 + threadIdx.x;
  if (i < nv) {
    f32x4 a = *(const f32x4*)(lg8 + (size_t)i * 8);
    f32x4 b = *(const f32x4*)(lg8 + (size_t)i * 8 + 4);
    out[i] = ((a[0]+a[1])+(a[2]+a[3])) + ((b[0]+b[1])+(b[2]+b[3])) + b3p[0];
  } else if (i == nv) {
    out[nv] = total[0] * (1.f/32.f);
  }
}

// ---------------- CSR build
__global__ void hist_k(const int* __restrict__ lit_idx, int* __restrict__ cnt, int E) {
  int e = blockIdx.x * 256 + threadIdx.x;
  if (e < E) atomicAdd(&cnt[lit_idx[e]], 1);
}
__global__ void scan1_k(const int* __restrict__ cnt, int* __restrict__ excl,
                        int* __restrict__ bsum, int n) {
  __shared__ int sm[256];
  int i = blockIdx.x * 256 + threadIdx.x;
  int v = (i < n) ? cnt[i] : 0;
  sm[threadIdx.x] = v;
  __syncthreads();
  for (int o = 1; o < 256; o <<= 1) {
    int add = (threadIdx.x >= o) ? sm[threadIdx.x - o] : 0;
    __syncthreads();
    sm[threadIdx.x] += add;
    __syncthreads();
  }
  if (i < n) excl[i] = sm[threadIdx.x] - v;
  if (threadIdx.x == 255) bsum[blockIdx.x] = sm[255];
}
__global__ void scan2_k(int* __restrict__ bsum, int nb) {
  __shared__ int sm[256];
  int v = (threadIdx.x < nb) ? bsum[threadIdx.x] : 0;
  sm[threadIdx.x] = v;
  __syncthreads();
  for (int o = 1; o < 256; o <<= 1) {
    int add = (threadIdx.x >= o) ? sm[threadIdx.x - o] : 0;
    __syncthreads();
    sm[threadIdx.x] += add;
    __syncthreads();
  }
  if (threadIdx.x < nb) bsum[threadIdx.x] = sm[threadIdx.x] - v;
}
__global__ void scan3_k(const int* __restrict__ excl, const int* __restrict__ bsum,
                        int* __restrict__ offs, int n, int E) {
  int i = blockIdx.x * 256 + threadIdx.x;
  if (i < n) offs[i] = excl[i] + bsum[i >> 8];
  if (i == 0) offs[n] = E;
}
__global__ void fill_k(const int* __restrict__ lit_idx, const int* __restrict__ offs,
                       int* __restrict__ cur, int* __restrict__ elist, int E) {
  int e = blockIdx.x * 256 + threadIdx.x;
  if (e >= E) return;
  int l = lit_idx[e];
  int p = offs[l] + atomicAdd(&cur[l], 1);
  elist[p] = e;
}

extern "C" void kernel_launch(void* const* d_in, const int* in_sizes, int n_in,
                              void* d_out, int out_size, void* d_ws, size_t ws_size,
                              hipStream_t stream) {
  (void)n_in;
  const float* L_init = (const float*)d_in[0];
  const float* C_init = (const float*)d_in[1];
  const float* attl_W = (const float*)d_in[2];
  const float* attl_b = (const float*)d_in[3];
  const float* attc_W = (const float*)d_in[4];
  const float* attc_b = (const float*)d_in[5];
  const float* lit_W  = (const float*)d_in[6];
  const float* lit_b  = (const float*)d_in[7];
  const float* cls_W  = (const float*)d_in[8];
  const float* cls_b  = (const float*)d_in[9];
  const float* ln_g   = (const float*)d_in[10];
  const float* ln_b   = (const float*)d_in[11];
  const float* outW1  = (const float*)d_in[12];
  const float* outb1  = (const float*)d_in[13];
  const float* outW2  = (const float*)d_in[14];
  const float* outb2  = (const float*)d_in[15];
  const float* outW3  = (const float*)d_in[16];
  const float* outb3  = (const float*)d_in[17];
  const int* lit_idx  = (const int*)d_in[18];
  const int* clauses  = (const int*)d_in[20];

  const int nv = out_size - 1;        // 20000
  const int NL = 2 * nv;              // 40000
  const int E  = in_sizes[18];        // 252000
  const int NC = in_sizes[20] / 3;    // 84000

  char* wp = (char*)d_ws;
  auto alloc = [&](size_t bytes) -> char* {
    char* p = wp; wp += (bytes + 255) & ~(size_t)255; return p;
  };

  short* TW     = (short*)alloc(sizeof(short) * (size_t)(12 * 65536 + 2 * 262144));
  short* T_attc = TW;
  short* T_cls  = TW + 3 * 65536;
  short* T_attl = TW + 6 * 65536;
  short* T_lit  = TW + 9 * 65536;
  short* T_o1   = TW + 12 * 65536;
  short* T_o2   = T_o1 + 262144;

  size_t PE = (size_t)NC * 256;
  if ((size_t)nv * 512 > PE) PE = (size_t)nv * 512;
  short* P0   = (short*)alloc(2 * PE);
  short* P1   = (short*)alloc(2 * PE);   // also holds KV_l [NL][512]
  short* c_st = (short*)alloc(2 * (size_t)NC * 256);
  short* l_st = (short*)alloc(2 * (size_t)NL * 256);
  short* c1b  = (short*)alloc(2 * (size_t)NC * 256);
  short* l1b  = (short*)alloc(2 * (size_t)NL * 256);   // also holds vote h1 [nv][512]
  float* lg8  = (float*)alloc(4 * (size_t)nv * 8);
  float* total = (float*)alloc(256);
  int* cnt   = (int*)alloc(4 * (size_t)NL);
  int* cur   = (int*)alloc(4 * (size_t)NL);
  int* offs  = (int*)alloc(4 * (size_t)(NL + 1));
  int* excl  = (int*)alloc(4 * (size_t)NL);
  int* bsum  = (int*)alloc(4 * 256);
  int* elist = (int*)alloc(4 * (size_t)E);

  if ((size_t)(wp - (char*)d_ws) > ws_size) return;

  zero_i32_k<<<dim3((NL + 255) / 256), dim3(256), 0, stream>>>(cnt, NL);
  zero_i32_k<<<dim3((NL + 255) / 256), dim3(256), 0, stream>>>(cur, NL);
  zero_f32_k<<<dim3(1), dim3(256), 0, stream>>>(total, 1);

  auto tps = [&](const float* src, short* dst, int Kd, int Nd) {
    int tot = Kd * Nd;
    transpose_k<<<dim3((tot + 255) / 256), dim3(256), 0, stream>>>(src, dst, Kd, Nd);
  };
  for (int j = 0; j < 3; ++j) {
    tps(attc_W + j * 65536, T_attc + j * 65536, 256, 256);
    tps(cls_W  + j * 65536, T_cls  + j * 65536, 256, 256);
    tps(attl_W + j * 65536, T_attl + j * 65536, 256, 256);
    tps(lit_W  + j * 65536, T_lit  + j * 65536, 256, 256);
  }
  tps(outW1, T_o1, 512, 512);
  tps(outW2, T_o2, 512, 512);

  int nb = (NL + 255) / 256;
  hist_k<<<dim3((E + 255) / 256), dim3(256), 0, stream>>>(lit_idx, cnt, E);
  scan1_k<<<dim3(nb), dim3(256), 0, stream>>>(cnt, excl, bsum, NL);
  scan2_k<<<dim3(1), dim3(256), 0, stream>>>(bsum, nb);
  scan3_k<<<dim3(nb), dim3(256), 0, stream>>>(excl, bsum, offs, NL, E);
  fill_k<<<dim3((E + 255) / 256), dim3(256), 0, stream>>>(lit_idx, offs, cur, elist, E);

  init_state_k<<<dim3(((NC * 256) + 255) / 256), dim3(256), 0, stream>>>(C_init, c_st, NC);
  init_state_k<<<dim3(((NL * 256) + 255) / 256), dim3(256), 0, stream>>>(L_init, l_st, NL);

  dim3 gC((NC + 3) / 4), gL((NL + 3) / 4);

  const int mtC = (NC + 127) / 128;   // 657
  const int mtL = (NL + 127) / 128;   // 313
  const int mtV = (nv + 127) / 128;   // 157

  for (int rd = 0; rd < 32; ++rd) {
    int vblk = (rd > 0) ? mtV * 4 : 0;
    // ---- launch A: Qc(r), KVl(r), vote1(r-1) -> h1 in l1b
    {
      Seg sQc  { c_st, T_attc,         attc_b,       P0, nullptr, NC, mtC * 2, 2, 256, 256, 0, 0, 0, 0 };
      Seg sKVl { l_st, T_attc + 65536, attc_b + 256, P1, nullptr, NL, mtL * 4, 4, 512, 256, 0, 0, 0, 0 };
      Seg sV1  { l_st, T_o1,           outb1,        l1b, nullptr, nv, vblk,   4, 512, 512, 1, 1, 0, nv };
      gemm_multi3_k<<<dim3(sQc.nblk + sKVl.nblk + sV1.nblk), dim3(256), 0, stream>>>(
          sQc, sKVl, sV1, nullptr, nullptr);
    }
    clause_attn_k<<<gC, dim3(256), 0, stream>>>(P0, P1, lit_idx, c_st,
                                                ln_g + 0, ln_b + 0, c1b, NC);     // c1
    mlp3ln_k<<<dim3((NC + 63) / 64), dim3(512), 0, stream>>>(
        c1b, T_cls, T_cls + 65536, T_cls + 2 * 65536, cls_b, cls_b + 256, cls_b + 512,
        ln_g + 3*256, ln_b + 3*256, c_st, NC);                                    // c2

    // ---- launch B: Ql(r), Kc|Vc(r), vote2(r-1) logits -> lg8
    {
      Seg sQl  { l_st, T_attl,         attl_b,       P0, nullptr, NL, mtL * 2, 2, 256, 256, 0, 0, 0, 0 };
      Seg sKVc { c_st, T_attl + 65536, attl_b + 256, P1, c1b,     NC, mtC * 4, 4, 256, 256, 0, 0, 0, 0 };
      Seg sV2  { l1b,  T_o2,           outb2,        nullptr, nullptr, nv, vblk, 4, 512, 512, 1, 0, 1, 0 };
      gemm_multi3_k<<<dim3(sQl.nblk + sKVc.nblk + sV2.nblk), dim3(256), 0, stream>>>(
          sQl, sKVc, sV2, outW3, lg8);
    }
    if (rd > 0)
      loss_k<<<dim3((NC + 255) / 256), dim3(256), 0, stream>>>(clauses, lg8, outb3, total, NC);

    lit_attn_k<<<gL, dim3(256), 0, stream>>>(P0, P1, c1b, offs, elist, l_st,
                                             ln_g + 256, ln_b + 256, l1b, NL, nv); // l1
    mlp3ln_k<<<dim3((NL + 63) / 64), dim3(512), 0, stream>>>(
        l1b, T_lit, T_lit + 65536, T_lit + 2 * 65536, lit_b, lit_b + 256, lit_b + 512,
        ln_g + 2*256, ln_b + 2*256, l_st, NL);                                    // l2
  }

  // ---- drain: vote chain for round 31
  {
    dim3 grd(mtV * 4);
    gemm_lds_k<1,512,512,1,0,4><<<grd, dim3(256), 0, stream>>>(l_st, T_o1, outb1, l1b, nv, nv, nullptr, nullptr);
    gemm_lds_k<1,512,512,0,1,4><<<grd, dim3(256), 0, stream>>>(l1b, T_o2, outb2, nullptr, nv, 0, outW3, lg8);
    loss_k<<<dim3((NC + 255) / 256), dim3(256), 0, stream>>>(clauses, lg8, outb3, total, NC);
  }

  writeout_k<<<dim3((nv + 256) / 256), dim3(256), 0, stream>>>(lg8, outb3, total, (float*)d_out, nv);
}